// Round 2
// baseline (12667.378 us; speedup 1.0000x reference)
//
#include <hip/hip_runtime.h>
#include <hip/hip_bf16.h>
#include <math.h>

// Problem constants
#define DIM 4096
#define N_HEADS 32
#define N_KV_HEADS 8
#define HEAD_DIM 128
#define N_REP 4
#define BSZ 2
#define SEQLEN 2048
#define BS (BSZ * SEQLEN)          // 4096 rows
#define KV_DIM (N_KV_HEADS * HEAD_DIM)  // 1024

// ---------------------------------------------------------------------------
// Tiled GEMM: C[M,N] = A[M,K] @ B[K,N], fp32 in / fp32 accumulate / fp32 out.
// BM=BN=64, BK=16, 256 threads, each thread computes a 4x4 microtile.
// M,N,K must be multiples of 64/64/16 (they are: 4096 / 4096-or-1024 / 4096).
// ---------------------------------------------------------------------------
__global__ __launch_bounds__(256) void gemm_tiled(const float* __restrict__ A,
                                                  const float* __restrict__ B,
                                                  float* __restrict__ C,
                                                  int M, int N, int K) {
    __shared__ float As[16][64];   // [k][m]
    __shared__ float Bs[16][64];   // [k][n]

    const int tid = threadIdx.x;
    const int bm = blockIdx.y * 64;
    const int bn = blockIdx.x * 64;

    // compute microtile coords
    const int tm = (tid / 16) * 4;
    const int tn = (tid % 16) * 4;

    // A-load mapping: row = tid/4 (0..63), 4 consecutive k at (tid%4)*4
    const int ar = tid >> 2;
    const int ac = (tid & 3) * 4;
    // B-load mapping: k-row = tid/16 (0..15), 4 consecutive n at (tid%16)*4
    const int br = tid >> 4;
    const int bc = (tid & 15) * 4;

    float acc[4][4] = {};

    for (int k0 = 0; k0 < K; k0 += 16) {
        // stage A tile (64 rows x 16 k), store transposed As[k][m]
        const float* Ap = A + (size_t)(bm + ar) * K + k0 + ac;
        float4 av = *(const float4*)Ap;
        As[ac + 0][ar] = av.x;
        As[ac + 1][ar] = av.y;
        As[ac + 2][ar] = av.z;
        As[ac + 3][ar] = av.w;
        // stage B tile (16 k x 64 n)
        const float* Bp = B + (size_t)(k0 + br) * N + bn + bc;
        float4 bv = *(const float4*)Bp;
        *(float4*)&Bs[br][bc] = bv;
        __syncthreads();

#pragma unroll
        for (int k = 0; k < 16; ++k) {
            float a[4], b[4];
#pragma unroll
            for (int i = 0; i < 4; ++i) a[i] = As[k][tm + i];
#pragma unroll
            for (int j = 0; j < 4; ++j) b[j] = Bs[k][tn + j];
#pragma unroll
            for (int i = 0; i < 4; ++i)
#pragma unroll
                for (int j = 0; j < 4; ++j) acc[i][j] += a[i] * b[j];
        }
        __syncthreads();
    }

#pragma unroll
    for (int i = 0; i < 4; ++i) {
        size_t row = (size_t)(bm + tm + i);
        float4 ov = make_float4(acc[i][0], acc[i][1], acc[i][2], acc[i][3]);
        *(float4*)&C[row * N + bn + tn] = ov;
    }
}

// ---------------------------------------------------------------------------
// RoPE (interleaved pairs), in-place on fp32 intermediate.
// t layout: (BS, n_heads*128). pair p covers dims (2p, 2p+1).
// ---------------------------------------------------------------------------
__global__ void rope_kernel(float* __restrict__ t,
                            const float* __restrict__ cosb,
                            const float* __restrict__ sinb,
                            int n_heads, int total_pairs) {
    int idx = blockIdx.x * blockDim.x + threadIdx.x;
    if (idx >= total_pairs) return;
    int p = idx & 63;                 // pair index 0..63
    int h = (idx >> 6) % n_heads;
    int bs = idx / (64 * n_heads);    // 0..BS-1
    int s = bs & (SEQLEN - 1);        // seq position (start_pos = 0)

    float c = cosb[s * 64 + p];
    float sn = sinb[s * 64 + p];

    size_t base = (size_t)bs * (n_heads * HEAD_DIM) + h * HEAD_DIM + 2 * p;
    float e = t[base];
    float o = t[base + 1];
    t[base]     = e * c - o * sn;
    t[base + 1] = e * sn + o * c;
}

// ---------------------------------------------------------------------------
// Flash-style causal attention with online softmax.
// Grid: (q_tiles=64, heads=32, batch=2). Block: 256 threads.
// Q tile = 32 rows x 128; iterate K/V tiles of 32 rows.
// Each thread owns (row = tid/8, 16 dims at (tid%8)*16).
// ---------------------------------------------------------------------------
#define LP 129  // padded LDS row stride (breaks bank conflicts)

__global__ __launch_bounds__(256) void flash_attn(const float* __restrict__ xq,
                                                  const float* __restrict__ xk,
                                                  const float* __restrict__ xv,
                                                  float* __restrict__ ctx) {
    __shared__ float Qs[32 * LP];
    __shared__ float Ks[32 * LP];
    __shared__ float Vs[32 * LP];
    __shared__ float Ss[32 * 33];

    const int qt = blockIdx.x;       // 0..63
    const int h  = blockIdx.y;       // 0..31
    const int b  = blockIdx.z;       // 0..1
    const int hkv = h >> 2;          // GQA: 4 q-heads share a kv-head

    const int tid = threadIdx.x;
    const int r  = tid >> 3;          // row 0..31 (load + update role)
    const int d0 = (tid & 7) * 16;    // dim base

    const int sr  = tid >> 3;         // score row
    const int sc0 = (tid & 7) * 4;    // score col base (4 cols/thread)

    const float scale = 0.08838834764831845f;  // 1/sqrt(128)
    const int q0 = qt * 32;

    // Load Q tile (pre-scaled)
    {
        const float* qp = xq + (size_t)(b * SEQLEN + q0 + r) * DIM + h * HEAD_DIM + d0;
#pragma unroll
        for (int i = 0; i < 16; ++i) Qs[r * LP + d0 + i] = qp[i] * scale;
    }

    float m_i = -INFINITY;
    float l_i = 0.f;
    float acc[16] = {};

    for (int kt = 0; kt <= qt; ++kt) {
        const int k0 = kt * 32;
        __syncthreads();  // protect Ks/Vs/Ss from previous iteration readers
        {
            const float* kp = xk + (size_t)(b * SEQLEN + k0 + r) * KV_DIM + hkv * HEAD_DIM + d0;
            const float* vp = xv + (size_t)(b * SEQLEN + k0 + r) * KV_DIM + hkv * HEAD_DIM + d0;
#pragma unroll
            for (int i = 0; i < 16; ++i) {
                Ks[r * LP + d0 + i] = kp[i];
                Vs[r * LP + d0 + i] = vp[i];
            }
        }
        __syncthreads();

        // scores: 4 per thread
        float s[4] = {};
        for (int d = 0; d < HEAD_DIM; ++d) {
            float qv = Qs[sr * LP + d];
#pragma unroll
            for (int j = 0; j < 4; ++j) s[j] += qv * Ks[(sc0 + j) * LP + d];
        }
        if (kt == qt) {
#pragma unroll
            for (int j = 0; j < 4; ++j)
                if (k0 + sc0 + j > q0 + sr) s[j] = -1e30f;
        }
#pragma unroll
        for (int j = 0; j < 4; ++j) Ss[sr * 33 + sc0 + j] = s[j];
        __syncthreads();

        // online softmax update (8 threads per row do redundant identical math)
        float tmax = -INFINITY;
#pragma unroll
        for (int j = 0; j < 32; ++j) tmax = fmaxf(tmax, Ss[r * 33 + j]);
        float new_m = fmaxf(m_i, tmax);
        float alpha = expf(m_i - new_m);  // first iter: exp(-inf - finite) = 0
        float psum = 0.f;
        float p[32];
#pragma unroll
        for (int j = 0; j < 32; ++j) {
            p[j] = expf(Ss[r * 33 + j] - new_m);
            psum += p[j];
        }
        l_i = alpha * l_i + psum;
        m_i = new_m;
#pragma unroll
        for (int i = 0; i < 16; ++i) acc[i] *= alpha;
        for (int j = 0; j < 32; ++j) {
            float pj = p[j];
#pragma unroll
            for (int i = 0; i < 16; ++i) acc[i] += pj * Vs[j * LP + d0 + i];
        }
    }

    // write ctx in (b, s, h*128+d) layout  (diag always unmasked -> l_i > 0)
    float inv_l = 1.0f / l_i;
    float* op = ctx + (size_t)(b * SEQLEN + q0 + r) * DIM + h * HEAD_DIM + d0;
#pragma unroll
    for (int i = 0; i < 16; ++i) op[i] = acc[i] * inv_l;
}

// ---------------------------------------------------------------------------
// kernel_launch
// inputs: x, wq, wk, wv, wo, freqs_cos, freqs_sin, mask, start_pos
// All float32 per the reference (start_pos is int scalar, unused: always 0).
// ---------------------------------------------------------------------------
extern "C" void kernel_launch(void* const* d_in, const int* in_sizes, int n_in,
                              void* d_out, int out_size, void* d_ws, size_t ws_size,
                              hipStream_t stream) {
    const float* x   = (const float*)d_in[0];
    const float* wq  = (const float*)d_in[1];
    const float* wk  = (const float*)d_in[2];
    const float* wv  = (const float*)d_in[3];
    const float* wo  = (const float*)d_in[4];
    const float* fc  = (const float*)d_in[5];
    const float* fs  = (const float*)d_in[6];
    // d_in[7] = mask (unused; causal mask applied analytically)
    // d_in[8] = start_pos (always 0)
    float* out = (float*)d_out;

    float* ws = (float*)d_ws;
    float* xq  = ws;                                     // BS*4096 fp32
    float* xk  = xq + (size_t)BS * DIM;                  // BS*1024
    float* xv  = xk + (size_t)BS * KV_DIM;               // BS*1024
    float* ctx = xv + (size_t)BS * KV_DIM;               // BS*4096

    // 1) QKV projections
    {
        dim3 grid(DIM / 64, BS / 64);
        gemm_tiled<<<grid, 256, 0, stream>>>(x, wq, xq, BS, DIM, DIM);
    }
    {
        dim3 grid(KV_DIM / 64, BS / 64);
        gemm_tiled<<<grid, 256, 0, stream>>>(x, wk, xk, BS, KV_DIM, DIM);
        gemm_tiled<<<grid, 256, 0, stream>>>(x, wv, xv, BS, KV_DIM, DIM);
    }

    // 2) RoPE on xq and xk
    {
        int total_q = BS * N_HEADS * 64;
        rope_kernel<<<(total_q + 255) / 256, 256, 0, stream>>>(xq, fc, fs, N_HEADS, total_q);
        int total_k = BS * N_KV_HEADS * 64;
        rope_kernel<<<(total_k + 255) / 256, 256, 0, stream>>>(xk, fc, fs, N_KV_HEADS, total_k);
    }

    // 3) Flash attention
    {
        dim3 grid(SEQLEN / 32, N_HEADS, BSZ);
        flash_attn<<<grid, 256, 0, stream>>>(xq, xk, xv, ctx);
    }

    // 4) Output projection -> fp32 out
    {
        dim3 grid(DIM / 64, BS / 64);
        gemm_tiled<<<grid, 256, 0, stream>>>(ctx, wo, out, BS, DIM, DIM);
    }
}

// Round 3
// 4945.798 us; speedup vs baseline: 2.5612x; 2.5612x over previous
//
#include <hip/hip_runtime.h>
#include <hip/hip_bf16.h>
#include <math.h>
#include <stdint.h>

// Problem constants
#define DIM 4096
#define N_HEADS 32
#define N_KV_HEADS 8
#define HEAD_DIM 128
#define BSZ 2
#define SEQLEN 2048
#define BS (BSZ * SEQLEN)               // 4096 rows
#define KV_DIM (N_KV_HEADS * HEAD_DIM)  // 1024

typedef unsigned short u16;
typedef __attribute__((ext_vector_type(8))) short bf16x8;
typedef __attribute__((ext_vector_type(4))) float f32x4;
typedef __attribute__((ext_vector_type(8))) unsigned short u16x8;
typedef __attribute__((ext_vector_type(4))) unsigned short u16x4;

__device__ __forceinline__ u16 f2bf(float f) {
    __hip_bfloat16 h = __float2bfloat16(f);
    return *reinterpret_cast<u16*>(&h);
}
__device__ __forceinline__ float bf2f(u16 u) {
    __hip_bfloat16 h;
    *reinterpret_cast<u16*>(&h) = u;
    return __bfloat162float(h);
}

// ---------------------------------------------------------------------------
// cvt: fp32 -> bf16, 4 elems/thread
// ---------------------------------------------------------------------------
__global__ void cvt_f32_bf16(const float* __restrict__ in, u16* __restrict__ out, int n4) {
    int i = blockIdx.x * blockDim.x + threadIdx.x;
    if (i >= n4) return;
    float4 v = reinterpret_cast<const float4*>(in)[i];
    u16x4 o;
    o.x = f2bf(v.x); o.y = f2bf(v.y); o.z = f2bf(v.z); o.w = f2bf(v.w);
    reinterpret_cast<u16x4*>(out)[i] = o;
}

// ---------------------------------------------------------------------------
// transpose + cvt: in[K][N] fp32 -> out[N][K] bf16.  block (32,8), 32x32 tile.
// ---------------------------------------------------------------------------
__global__ __launch_bounds__(256) void transpose_f32_bf16(const float* __restrict__ in,
                                                          u16* __restrict__ out,
                                                          int K, int N) {
    __shared__ float tile[32][33];
    const int tx = threadIdx.x, ty = threadIdx.y;
    const int n0 = blockIdx.x * 32, k0 = blockIdx.y * 32;
#pragma unroll
    for (int i = 0; i < 4; ++i)
        tile[ty + 8 * i][tx] = in[(size_t)(k0 + ty + 8 * i) * N + n0 + tx];
    __syncthreads();
#pragma unroll
    for (int i = 0; i < 4; ++i)
        out[(size_t)(n0 + ty + 8 * i) * K + k0 + tx] = f2bf(tile[tx][ty + 8 * i]);
}

// ---------------------------------------------------------------------------
// MFMA bf16 GEMM:  C[M,N] = A[M,K] @ B[K,N]  with B given TRANSPOSED (BT[N,K]).
// 128x128 tile, BK=64, 256 threads = 4 waves (2x2 of 64x64 quadrants),
// mfma_f32_16x16x32_bf16, 4x4 fragments per wave.
// Staging via global_load_lds width=16; LDS chunk layout XOR-swizzled:
//   chunk (row, c) (c = k/8) lives at linear chunk index row*8 + (c ^ (row&7))
//   -> fragment ds_read_b128 spreads over all 8 bank-groups (2-way = free),
//   -> staging stays lane-contiguous in LDS and 128B-coalesced in global.
// ---------------------------------------------------------------------------
template <bool OUT_BF16>
__global__ __launch_bounds__(256) void gemm_mfma_bt(const u16* __restrict__ A,
                                                    const u16* __restrict__ BT,
                                                    void* __restrict__ Cv,
                                                    int M, int N, int K) {
    __shared__ __align__(16) u16 Al[128 * 64];
    __shared__ __align__(16) u16 Bl[128 * 64];

    const int tid  = threadIdx.x;
    const int wave = tid >> 6;
    const int lane = tid & 63;
    const int quad = lane >> 4;
    const int lm   = lane & 15;
    const size_t bm = (size_t)blockIdx.y * 128;
    const size_t bn = (size_t)blockIdx.x * 128;
    const int wm = (wave & 1) * 64;
    const int wn = (wave >> 1) * 64;

    // staging geometry (same for A and B): per instr, wave covers 8 rows x 64 k
    const int slot = lane & 7;                       // 16B chunk slot within row
    const int lrow = lane >> 3;                      // 0..7 row within instr
    const int csw  = slot ^ (lrow & 7);              // swizzled chunk col (row%8 == lrow%8)

    f32x4 acc[4][4] = {};

    for (int k0 = 0; k0 < K; k0 += 64) {
        __syncthreads();
#pragma unroll
        for (int i = 0; i < 4; ++i) {
            const int mloc = wave * 32 + i * 8 + lrow;   // 0..127 (mloc%8 == lrow)
            const u16* gA = A  + (bm + mloc) * (size_t)K + k0 + csw * 8;
            const u16* gB = BT + (bn + mloc) * (size_t)K + k0 + csw * 8;
            u16* lA = &Al[(mloc * 8 + slot) * 8];
            u16* lB = &Bl[(mloc * 8 + slot) * 8];
            __builtin_amdgcn_global_load_lds(
                reinterpret_cast<const __attribute__((address_space(1))) uint32_t*>(
                    reinterpret_cast<uintptr_t>(gA)),
                reinterpret_cast<__attribute__((address_space(3))) uint32_t*>(
                    reinterpret_cast<uintptr_t>(lA)),
                16, 0, 0);
            __builtin_amdgcn_global_load_lds(
                reinterpret_cast<const __attribute__((address_space(1))) uint32_t*>(
                    reinterpret_cast<uintptr_t>(gB)),
                reinterpret_cast<__attribute__((address_space(3))) uint32_t*>(
                    reinterpret_cast<uintptr_t>(lB)),
                16, 0, 0);
        }
        __syncthreads();

#pragma unroll
        for (int ks8 = 0; ks8 < 8; ks8 += 4) {   // two k-steps of 32 (chunk cols 0..3, 4..7)
            bf16x8 af[4], bfr[4];
            const int cc = ks8 + quad;           // this lane's chunk col
#pragma unroll
            for (int i = 0; i < 4; ++i) {
                const int m = wm + 16 * i + lm;
                af[i]  = *(const bf16x8*)&Al[(m * 8 + (cc ^ (m & 7))) * 8];
                const int n = wn + 16 * i + lm;
                bfr[i] = *(const bf16x8*)&Bl[(n * 8 + (cc ^ (n & 7))) * 8];
            }
#pragma unroll
            for (int i = 0; i < 4; ++i)
#pragma unroll
                for (int j = 0; j < 4; ++j)
                    acc[i][j] = __builtin_amdgcn_mfma_f32_16x16x32_bf16(af[i], bfr[j], acc[i][j], 0, 0, 0);
        }
    }

    // epilogue: C/D layout col = lane&15, row = quad*4 + reg
#pragma unroll
    for (int i = 0; i < 4; ++i) {
        const int mrow = wm + 16 * i + quad * 4;
#pragma unroll
        for (int j = 0; j < 4; ++j) {
            const int ncol = wn + 16 * j + lm;
#pragma unroll
            for (int r = 0; r < 4; ++r) {
                const size_t off = (bm + mrow + r) * (size_t)N + bn + ncol;
                const float v = acc[i][j][r];
                if constexpr (OUT_BF16) ((u16*)Cv)[off] = f2bf(v);
                else                    ((float*)Cv)[off] = v;
            }
        }
    }
}

// ---------------------------------------------------------------------------
// RoPE (interleaved pairs), in-place on bf16. t layout: (BS, n_heads*128).
// ---------------------------------------------------------------------------
__global__ void rope_kernel(u16* __restrict__ t,
                            const float* __restrict__ cosb,
                            const float* __restrict__ sinb,
                            int n_heads, int total_pairs) {
    int idx = blockIdx.x * blockDim.x + threadIdx.x;
    if (idx >= total_pairs) return;
    int p = idx & 63;
    int h = (idx >> 6) % n_heads;
    int bs = idx / (64 * n_heads);
    int s = bs & (SEQLEN - 1);        // start_pos = 0

    float c = cosb[s * 64 + p];
    float sn = sinb[s * 64 + p];

    size_t base = (size_t)bs * (n_heads * HEAD_DIM) + h * HEAD_DIM + 2 * p;
    float e = bf2f(t[base]);
    float o = bf2f(t[base + 1]);
    t[base]     = f2bf(e * c - o * sn);
    t[base + 1] = f2bf(e * sn + o * c);
}

// ---------------------------------------------------------------------------
// Flash-style causal attention, online softmax. bf16 in / bf16 ctx out,
// fp32 LDS math. Grid (64, 32, 2), 256 threads.
// PV/output mapping is stride-8 interleaved -> conflict-free Vs reads.
// ---------------------------------------------------------------------------
#define LP 129

__global__ __launch_bounds__(256) void flash_attn(const u16* __restrict__ xq,
                                                  const u16* __restrict__ xk,
                                                  const u16* __restrict__ xv,
                                                  u16* __restrict__ ctx) {
    __shared__ float Qs[32 * LP];
    __shared__ float Ks[32 * LP];
    __shared__ float Vs[32 * LP];
    __shared__ float Ss[32 * 33];

    const int qt = blockIdx.x;
    const int h  = blockIdx.y;
    const int b  = blockIdx.z;
    const int hkv = h >> 2;

    const int tid = threadIdx.x;
    const int r   = tid >> 3;          // row 0..31 (staging + PV row)
    const int d0  = (tid & 7) * 16;    // staging dim base (consecutive 16)
    const int dd0 = tid & 7;           // PV dim base (stride-8 interleave)

    const int sr  = tid >> 3;          // score row
    const int sc0 = (tid & 7) * 4;     // score col base

    const float scale = 0.08838834764831845f;  // 1/sqrt(128)
    const int q0 = qt * 32;

    // Load Q tile (pre-scaled)
    {
        const u16* qp = xq + (size_t)(b * SEQLEN + q0 + r) * DIM + h * HEAD_DIM + d0;
        u16x8 a = *(const u16x8*)qp;
        u16x8 bb = *(const u16x8*)(qp + 8);
#pragma unroll
        for (int i = 0; i < 8; ++i) {
            Qs[r * LP + d0 + i]     = bf2f(a[i]) * scale;
            Qs[r * LP + d0 + 8 + i] = bf2f(bb[i]) * scale;
        }
    }

    float m_i = -INFINITY;
    float l_i = 0.f;
    float acc[16] = {};

    for (int kt = 0; kt <= qt; ++kt) {
        const int k0 = kt * 32;
        __syncthreads();
        {
            const u16* kp = xk + (size_t)(b * SEQLEN + k0 + r) * KV_DIM + hkv * HEAD_DIM + d0;
            const u16* vp = xv + (size_t)(b * SEQLEN + k0 + r) * KV_DIM + hkv * HEAD_DIM + d0;
            u16x8 k1 = *(const u16x8*)kp;
            u16x8 k2 = *(const u16x8*)(kp + 8);
            u16x8 v1 = *(const u16x8*)vp;
            u16x8 v2 = *(const u16x8*)(vp + 8);
#pragma unroll
            for (int i = 0; i < 8; ++i) {
                Ks[r * LP + d0 + i]     = bf2f(k1[i]);
                Ks[r * LP + d0 + 8 + i] = bf2f(k2[i]);
                Vs[r * LP + d0 + i]     = bf2f(v1[i]);
                Vs[r * LP + d0 + 8 + i] = bf2f(v2[i]);
            }
        }
        __syncthreads();

        // scores: 4 per thread
        float s[4] = {};
        for (int d = 0; d < HEAD_DIM; ++d) {
            float qv = Qs[sr * LP + d];
#pragma unroll
            for (int j = 0; j < 4; ++j) s[j] += qv * Ks[(sc0 + j) * LP + d];
        }
        if (kt == qt) {
#pragma unroll
            for (int j = 0; j < 4; ++j)
                if (k0 + sc0 + j > q0 + sr) s[j] = -1e30f;
        }
#pragma unroll
        for (int j = 0; j < 4; ++j) Ss[sr * 33 + sc0 + j] = s[j];
        __syncthreads();

        // online softmax update (8 threads per row duplicate the row math)
        float tmax = -INFINITY;
#pragma unroll
        for (int j = 0; j < 32; ++j) tmax = fmaxf(tmax, Ss[r * 33 + j]);
        float new_m = fmaxf(m_i, tmax);
        float alpha = expf(m_i - new_m);
        float psum = 0.f;
        float p[32];
#pragma unroll
        for (int j = 0; j < 32; ++j) {
            p[j] = expf(Ss[r * 33 + j] - new_m);
            psum += p[j];
        }
        l_i = alpha * l_i + psum;
        m_i = new_m;
#pragma unroll
        for (int i = 0; i < 16; ++i) acc[i] *= alpha;
        for (int j = 0; j < 32; ++j) {
            float pj = p[j];
#pragma unroll
            for (int i = 0; i < 16; ++i) acc[i] += pj * Vs[j * LP + dd0 + 8 * i];
        }
    }

    // write ctx (bf16) — thread owns dims dd0 + 8*i of row q0+r
    float inv_l = 1.0f / l_i;
    u16* op = ctx + (size_t)(b * SEQLEN + q0 + r) * DIM + h * HEAD_DIM;
#pragma unroll
    for (int i = 0; i < 16; ++i) op[dd0 + 8 * i] = f2bf(acc[i] * inv_l);
}

// ---------------------------------------------------------------------------
// kernel_launch
// inputs: x, wq, wk, wv, wo, freqs_cos, freqs_sin, mask, start_pos (all fp32)
// ---------------------------------------------------------------------------
extern "C" void kernel_launch(void* const* d_in, const int* in_sizes, int n_in,
                              void* d_out, int out_size, void* d_ws, size_t ws_size,
                              hipStream_t stream) {
    const float* x   = (const float*)d_in[0];
    const float* wq  = (const float*)d_in[1];
    const float* wk  = (const float*)d_in[2];
    const float* wv  = (const float*)d_in[3];
    const float* wo  = (const float*)d_in[4];
    const float* fc  = (const float*)d_in[5];
    const float* fs  = (const float*)d_in[6];
    float* out = (float*)d_out;

    // ws carve-up: exactly 160 MiB total (same footprint as known-good R2)
    u16* x_bf = (u16*)d_ws;                       // [4096][4096]
    u16* wqT  = x_bf + (size_t)BS * DIM;          // [4096][4096]
    u16* wkT  = wqT + (size_t)DIM * DIM;          // [1024][4096]
    u16* wvT  = wkT + (size_t)KV_DIM * DIM;       // [1024][4096]
    u16* woT  = wvT + (size_t)KV_DIM * DIM;       // [4096][4096]
    u16* xq   = woT + (size_t)DIM * DIM;          // [4096][4096]
    u16* xk   = xq + (size_t)BS * DIM;            // [4096][1024]
    u16* xv   = xk + (size_t)BS * KV_DIM;         // [4096][1024]
    u16* ctx  = x_bf;                             // alias x_bf (dead after QKV GEMMs)

    // 0) converts
    {
        int n4 = BS * DIM / 4;
        cvt_f32_bf16<<<(n4 + 255) / 256, 256, 0, stream>>>(x, x_bf, n4);
        dim3 blk(32, 8);
        transpose_f32_bf16<<<dim3(DIM / 32, DIM / 32), blk, 0, stream>>>(wq, wqT, DIM, DIM);
        transpose_f32_bf16<<<dim3(KV_DIM / 32, DIM / 32), blk, 0, stream>>>(wk, wkT, DIM, KV_DIM);
        transpose_f32_bf16<<<dim3(KV_DIM / 32, DIM / 32), blk, 0, stream>>>(wv, wvT, DIM, KV_DIM);
        transpose_f32_bf16<<<dim3(DIM / 32, DIM / 32), blk, 0, stream>>>(wo, woT, DIM, DIM);
    }

    // 1) QKV projections (MFMA)
    gemm_mfma_bt<true><<<dim3(DIM / 128, BS / 128), 256, 0, stream>>>(x_bf, wqT, xq, BS, DIM, DIM);
    gemm_mfma_bt<true><<<dim3(KV_DIM / 128, BS / 128), 256, 0, stream>>>(x_bf, wkT, xk, BS, KV_DIM, DIM);
    gemm_mfma_bt<true><<<dim3(KV_DIM / 128, BS / 128), 256, 0, stream>>>(x_bf, wvT, xv, BS, KV_DIM, DIM);

    // 2) RoPE
    {
        int total_q = BS * N_HEADS * 64;
        rope_kernel<<<(total_q + 255) / 256, 256, 0, stream>>>(xq, fc, fs, N_HEADS, total_q);
        int total_k = BS * N_KV_HEADS * 64;
        rope_kernel<<<(total_k + 255) / 256, 256, 0, stream>>>(xk, fc, fs, N_KV_HEADS, total_k);
    }

    // 3) Flash attention -> bf16 ctx
    flash_attn<<<dim3(SEQLEN / 32, N_HEADS, BSZ), 256, 0, stream>>>(xq, xk, xv, ctx);

    // 4) Output projection (MFMA) -> fp32 out
    gemm_mfma_bt<false><<<dim3(DIM / 128, BS / 128), 256, 0, stream>>>(ctx, woT, out, BS, DIM, DIM);
}